// Round 1
// baseline (348.564 us; speedup 1.0000x reference)
//
#include <hip/hip_runtime.h>

#define N_IMG 128
#define BINS 128
#define HW_ELEMS (1 << 20)   // 1024*1024, C=1
#define CHUNKS 16            // blocks per image for histogram

// ---------------- Kernel 1: per-image histogram ----------------
__global__ __launch_bounds__(256) void hist_kernel(const float* __restrict__ x,
                                                   int* __restrict__ hist) {
    __shared__ int lh[4][BINS];  // per-wave privatized histograms
    const int tid  = threadIdx.x;
    const int wave = tid >> 6;

    for (int i = tid; i < 4 * BINS; i += 256) ((int*)lh)[i] = 0;
    __syncthreads();

    const int blk   = blockIdx.x;
    const int img   = blk / CHUNKS;
    const int chunk = blk % CHUNKS;
    const int chunk_elems = HW_ELEMS / CHUNKS;          // 65536
    const long long base = (long long)img * HW_ELEMS + (long long)chunk * chunk_elems;
    const float4* xv = (const float4*)(x + base);
    const int n4 = chunk_elems / 4;                     // 16384

    for (int i = tid; i < n4; i += 256) {
        float4 v = xv[i];
        float vals[4] = {v.x, v.y, v.z, v.w};
        #pragma unroll
        for (int k = 0; k < 4; ++k) {
            float f = vals[k];
            if (f >= 0.0f && f <= 1.0f) {
                int b = (int)(f * (float)BINS);
                b = b > (BINS - 1) ? (BINS - 1) : b;
                atomicAdd(&lh[wave][b], 1);
            }
        }
    }
    __syncthreads();

    for (int b = tid; b < BINS; b += 256) {
        int s = lh[0][b] + lh[1][b] + lh[2][b] + lh[3][b];
        atomicAdd(&hist[img * BINS + b], s);
    }
}

// ---------------- Kernel 2: per-image MLP -> scalar w ----------------
__global__ __launch_bounds__(128) void mlp_kernel(const int* __restrict__ hist,
                                                  const float* __restrict__ W1, const float* __restrict__ b1,
                                                  const float* __restrict__ W2, const float* __restrict__ b2,
                                                  const float* __restrict__ W3, const float* __restrict__ b3,
                                                  const float* __restrict__ W4, const float* __restrict__ b4,
                                                  float* __restrict__ wout) {
    __shared__ float h0[128], a1[32], a2[64], a3[128];
    const int img = blockIdx.x;
    const int t   = threadIdx.x;

    h0[t] = (float)hist[img * BINS + t];
    __syncthreads();

    if (t < 32) {
        float acc = b1[t];
        #pragma unroll 8
        for (int i = 0; i < 128; ++i) acc += h0[i] * W1[i * 32 + t];
        a1[t] = fmaxf(acc, 0.0f);
    }
    __syncthreads();

    if (t < 64) {
        float acc = b2[t];
        #pragma unroll 8
        for (int i = 0; i < 32; ++i) acc += a1[i] * W2[i * 64 + t];
        a2[t] = fmaxf(acc, 0.0f);
    }
    __syncthreads();

    {
        float acc = b3[t];
        #pragma unroll 8
        for (int i = 0; i < 64; ++i) acc += a2[i] * W3[i * 128 + t];
        a3[t] = fmaxf(acc, 0.0f);
    }
    __syncthreads();

    if (t == 0) {
        float acc = b4[0];
        for (int i = 0; i < 128; ++i) acc += a3[i] * W4[i];
        wout[img] = acc;
    }
}

// ---------------- Kernel 3: out = x * w[img] ----------------
__global__ __launch_bounds__(256) void scale_kernel(const float* __restrict__ x,
                                                    const float* __restrict__ w,
                                                    float* __restrict__ out,
                                                    long long n4) {
    const long long stride = (long long)gridDim.x * blockDim.x;
    const float4* xv = (const float4*)x;
    float4* ov = (float4*)out;
    for (long long i = (long long)blockIdx.x * blockDim.x + threadIdx.x; i < n4; i += stride) {
        int img = (int)(i >> 18);   // HW_ELEMS/4 = 2^18 float4 per image
        float s = w[img];
        float4 v = xv[i];
        v.x *= s; v.y *= s; v.z *= s; v.w *= s;
        ov[i] = v;
    }
}

extern "C" void kernel_launch(void* const* d_in, const int* in_sizes, int n_in,
                              void* d_out, int out_size, void* d_ws, size_t ws_size,
                              hipStream_t stream) {
    const float* x  = (const float*)d_in[0];
    const float* W1 = (const float*)d_in[1];
    const float* b1 = (const float*)d_in[2];
    const float* W2 = (const float*)d_in[3];
    const float* b2 = (const float*)d_in[4];
    const float* W3 = (const float*)d_in[5];
    const float* b3 = (const float*)d_in[6];
    const float* W4 = (const float*)d_in[7];
    const float* b4 = (const float*)d_in[8];
    // d_in[9] = bins (=128), hard-coded to match shapes

    int*   hist = (int*)d_ws;
    float* wout = (float*)((char*)d_ws + (size_t)N_IMG * BINS * sizeof(int));

    // zero histograms every call (harness poisons ws once, never restores)
    hipMemsetAsync(d_ws, 0, (size_t)N_IMG * BINS * sizeof(int), stream);

    hist_kernel<<<N_IMG * CHUNKS, 256, 0, stream>>>(x, hist);

    mlp_kernel<<<N_IMG, 128, 0, stream>>>(hist, W1, b1, W2, b2, W3, b3, W4, b4, wout);

    const long long n4 = (long long)N_IMG * HW_ELEMS / 4;
    scale_kernel<<<8192, 256, 0, stream>>>(x, wout, (float*)d_out, n4);
}

// Round 3
// 311.306 us; speedup vs baseline: 1.1197x; 1.1197x over previous
//
#include <hip/hip_runtime.h>

#define N_IMG 128
#define BINS 128
#define HW_ELEMS (1 << 20)   // 1024*1024, C=1
#define CHUNKS 16            // blocks per image for histogram
#define NCOPY 16             // privatized LDS histogram copies (one per 16 lanes)
#define HPAD 132             // 132 % 32 = 4 -> copies start on different banks

typedef float f32x4 __attribute__((ext_vector_type(4)));

// ---------------- Kernel 1: per-image partial histograms ----------------
// Each block handles one (img, chunk) and writes its own 128-bin partial
// histogram with plain stores -> no global atomics, no pre-zeroing memset.
__global__ __launch_bounds__(256) void hist_kernel(const float* __restrict__ x,
                                                   int* __restrict__ parthist) {
    __shared__ int lh[NCOPY * HPAD];
    const int tid = threadIdx.x;
    const int cpy = tid >> 4;            // 16 threads per copy

    for (int i = tid; i < NCOPY * HPAD; i += 256) lh[i] = 0;
    __syncthreads();

    const int blk   = blockIdx.x;
    const int img   = blk / CHUNKS;
    const int chunk = blk % CHUNKS;
    const int chunk_elems = HW_ELEMS / CHUNKS;          // 65536
    const long long base = (long long)img * HW_ELEMS + (long long)chunk * chunk_elems;
    const f32x4* xv = (const f32x4*)(x + base);
    const int n4 = chunk_elems / 4;                     // 16384

    int* myh = &lh[cpy * HPAD];

    for (int i = tid; i < n4; i += 256) {
        f32x4 v = xv[i];
        #pragma unroll
        for (int k = 0; k < 4; ++k) {
            float f = v[k];
            if (f >= 0.0f && f <= 1.0f) {
                int b = (int)(f * (float)BINS);
                b = b > (BINS - 1) ? (BINS - 1) : b;
                atomicAdd(&myh[b], 1);
            }
        }
    }
    __syncthreads();

    // reduce 16 copies -> partial histogram for this block
    if (tid < BINS) {
        int s = 0;
        #pragma unroll
        for (int c = 0; c < NCOPY; ++c) s += lh[c * HPAD + tid];
        parthist[blk * BINS + tid] = s;
    }
}

// ---------------- Kernel 2: per-image MLP -> scalar w ----------------
__global__ __launch_bounds__(128) void mlp_kernel(const int* __restrict__ parthist,
                                                  const float* __restrict__ W1, const float* __restrict__ b1,
                                                  const float* __restrict__ W2, const float* __restrict__ b2,
                                                  const float* __restrict__ W3, const float* __restrict__ b3,
                                                  const float* __restrict__ W4, const float* __restrict__ b4,
                                                  float* __restrict__ wout) {
    __shared__ float h0[128], a1[32], a2[64], a3[128];
    const int img = blockIdx.x;
    const int t   = threadIdx.x;

    {
        int s = 0;
        #pragma unroll
        for (int c = 0; c < CHUNKS; ++c)
            s += parthist[(img * CHUNKS + c) * BINS + t];
        h0[t] = (float)s;
    }
    __syncthreads();

    if (t < 32) {
        float acc = b1[t];
        #pragma unroll 8
        for (int i = 0; i < 128; ++i) acc += h0[i] * W1[i * 32 + t];
        a1[t] = fmaxf(acc, 0.0f);
    }
    __syncthreads();

    if (t < 64) {
        float acc = b2[t];
        #pragma unroll 8
        for (int i = 0; i < 32; ++i) acc += a1[i] * W2[i * 64 + t];
        a2[t] = fmaxf(acc, 0.0f);
    }
    __syncthreads();

    {
        float acc = b3[t];
        #pragma unroll 8
        for (int i = 0; i < 64; ++i) acc += a2[i] * W3[i * 128 + t];
        a3[t] = fmaxf(acc, 0.0f);
    }
    __syncthreads();

    if (t == 0) {
        float acc = b4[0];
        for (int i = 0; i < 128; ++i) acc += a3[i] * W4[i];
        wout[img] = acc;
    }
}

// ---------------- Kernel 3: out = x * w[img] ----------------
__global__ __launch_bounds__(256) void scale_kernel(const float* __restrict__ x,
                                                    const float* __restrict__ w,
                                                    float* __restrict__ out,
                                                    long long n4) {
    const long long stride = (long long)gridDim.x * blockDim.x;
    const f32x4* xv = (const f32x4*)x;
    f32x4* ov = (f32x4*)out;
    for (long long i = (long long)blockIdx.x * blockDim.x + threadIdx.x; i < n4; i += stride) {
        int img = (int)(i >> 18);   // HW_ELEMS/4 = 2^18 float4 per image
        float s = w[img];
        f32x4 v = xv[i];
        v *= s;
        __builtin_nontemporal_store(v, &ov[i]);   // don't evict x from L3
    }
}

extern "C" void kernel_launch(void* const* d_in, const int* in_sizes, int n_in,
                              void* d_out, int out_size, void* d_ws, size_t ws_size,
                              hipStream_t stream) {
    const float* x  = (const float*)d_in[0];
    const float* W1 = (const float*)d_in[1];
    const float* b1 = (const float*)d_in[2];
    const float* W2 = (const float*)d_in[3];
    const float* b2 = (const float*)d_in[4];
    const float* W3 = (const float*)d_in[5];
    const float* b3 = (const float*)d_in[6];
    const float* W4 = (const float*)d_in[7];
    const float* b4 = (const float*)d_in[8];
    // d_in[9] = bins (=128), hard-coded to match shapes

    int*   parthist = (int*)d_ws;                                   // 2048*128*4 = 1 MB
    float* wout = (float*)((char*)d_ws + (size_t)N_IMG * CHUNKS * BINS * sizeof(int));

    hist_kernel<<<N_IMG * CHUNKS, 256, 0, stream>>>(x, parthist);

    mlp_kernel<<<N_IMG, 128, 0, stream>>>(parthist, W1, b1, W2, b2, W3, b3, W4, b4, wout);

    const long long n4 = (long long)N_IMG * HW_ELEMS / 4;
    scale_kernel<<<8192, 256, 0, stream>>>(x, wout, (float*)d_out, n4);
}

// Round 4
// 308.669 us; speedup vs baseline: 1.1292x; 1.0085x over previous
//
#include <hip/hip_runtime.h>

#define N_IMG 128
#define BINS 128
#define HW_ELEMS (1 << 20)   // 1024*1024, C=1
#define CHUNKS 16            // blocks per image for histogram
#define NCOPY 16             // privatized LDS histogram copies (one per 16 lanes)
#define HPAD 132             // 132 % 32 = 4 -> copies start on different banks

typedef float f32x4 __attribute__((ext_vector_type(4)));

// ---------------- Kernel 1: per-image partial histograms ----------------
// Reads x FORWARD (leaves tail of x in L3 for the scale pass).
// Each block handles one (img, chunk) and writes its own 128-bin partial
// histogram with plain stores -> no global atomics, no pre-zeroing memset.
__global__ __launch_bounds__(256) void hist_kernel(const float* __restrict__ x,
                                                   int* __restrict__ parthist) {
    __shared__ int lh[NCOPY * HPAD];
    const int tid = threadIdx.x;
    const int cpy = tid >> 4;            // 16 threads per copy

    for (int i = tid; i < NCOPY * HPAD; i += 256) lh[i] = 0;
    __syncthreads();

    const int blk   = blockIdx.x;
    const int img   = blk / CHUNKS;
    const int chunk = blk % CHUNKS;
    const int chunk_elems = HW_ELEMS / CHUNKS;          // 65536
    const long long base = (long long)img * HW_ELEMS + (long long)chunk * chunk_elems;
    const f32x4* xv = (const f32x4*)(x + base);
    const int n4 = chunk_elems / 4;                     // 16384

    int* myh = &lh[cpy * HPAD];

    for (int i = tid; i < n4; i += 256) {
        f32x4 v = xv[i];
        #pragma unroll
        for (int k = 0; k < 4; ++k) {
            float f = v[k];
            if (f >= 0.0f && f <= 1.0f) {
                int b = (int)(f * (float)BINS);
                b = b > (BINS - 1) ? (BINS - 1) : b;
                atomicAdd(&myh[b], 1);
            }
        }
    }
    __syncthreads();

    // reduce 16 copies -> partial histogram for this block
    if (tid < BINS) {
        int s = 0;
        #pragma unroll
        for (int c = 0; c < NCOPY; ++c) s += lh[c * HPAD + tid];
        parthist[blk * BINS + tid] = s;
    }
}

// ---------------- Kernel 2: per-image MLP -> scalar w ----------------
__global__ __launch_bounds__(128) void mlp_kernel(const int* __restrict__ parthist,
                                                  const float* __restrict__ W1, const float* __restrict__ b1,
                                                  const float* __restrict__ W2, const float* __restrict__ b2,
                                                  const float* __restrict__ W3, const float* __restrict__ b3,
                                                  const float* __restrict__ W4, const float* __restrict__ b4,
                                                  float* __restrict__ wout) {
    __shared__ float h0[128], a1[32], a2[64], a3[128];
    const int img = blockIdx.x;
    const int t   = threadIdx.x;

    {
        int s = 0;
        #pragma unroll
        for (int c = 0; c < CHUNKS; ++c)
            s += parthist[(img * CHUNKS + c) * BINS + t];
        h0[t] = (float)s;
    }
    __syncthreads();

    if (t < 32) {
        float acc = b1[t];
        #pragma unroll 8
        for (int i = 0; i < 128; ++i) acc += h0[i] * W1[i * 32 + t];
        a1[t] = fmaxf(acc, 0.0f);
    }
    __syncthreads();

    if (t < 64) {
        float acc = b2[t];
        #pragma unroll 8
        for (int i = 0; i < 32; ++i) acc += a1[i] * W2[i * 64 + t];
        a2[t] = fmaxf(acc, 0.0f);
    }
    __syncthreads();

    {
        float acc = b3[t];
        #pragma unroll 8
        for (int i = 0; i < 64; ++i) acc += a2[i] * W3[i * 128 + t];
        a3[t] = fmaxf(acc, 0.0f);
    }
    __syncthreads();

    if (t == 0) {
        float acc = b4[0];
        for (int i = 0; i < 128; ++i) acc += a3[i] * W4[i];
        wout[img] = acc;
    }
}

// ---------------- Kernel 3: out = x * w[img], REVERSE order ----------------
// Reads x backward so the tail of x (still L3-resident from hist's forward
// sweep) hits in cache; ends with the head of x resident for the next
// replay's hist pass. Nontemporal stores keep the output stream from
// evicting x.
__global__ __launch_bounds__(256) void scale_kernel(const float* __restrict__ x,
                                                    const float* __restrict__ w,
                                                    float* __restrict__ out,
                                                    long long n4) {
    const long long stride = (long long)gridDim.x * blockDim.x;
    const f32x4* xv = (const f32x4*)x;
    f32x4* ov = (f32x4*)out;
    for (long long ii = (long long)blockIdx.x * blockDim.x + threadIdx.x; ii < n4; ii += stride) {
        long long i = n4 - 1 - ii;   // reverse sweep; wave still covers one contiguous 1KB segment
        int img = (int)(i >> 18);    // HW_ELEMS/4 = 2^18 float4 per image
        float s = w[img];
        f32x4 v = xv[i];
        v *= s;
        __builtin_nontemporal_store(v, &ov[i]);
    }
}

extern "C" void kernel_launch(void* const* d_in, const int* in_sizes, int n_in,
                              void* d_out, int out_size, void* d_ws, size_t ws_size,
                              hipStream_t stream) {
    const float* x  = (const float*)d_in[0];
    const float* W1 = (const float*)d_in[1];
    const float* b1 = (const float*)d_in[2];
    const float* W2 = (const float*)d_in[3];
    const float* b2 = (const float*)d_in[4];
    const float* W3 = (const float*)d_in[5];
    const float* b3 = (const float*)d_in[6];
    const float* W4 = (const float*)d_in[7];
    const float* b4 = (const float*)d_in[8];
    // d_in[9] = bins (=128), hard-coded to match shapes

    int*   parthist = (int*)d_ws;                                   // 2048*128*4 = 1 MB
    float* wout = (float*)((char*)d_ws + (size_t)N_IMG * CHUNKS * BINS * sizeof(int));

    hist_kernel<<<N_IMG * CHUNKS, 256, 0, stream>>>(x, parthist);

    mlp_kernel<<<N_IMG, 128, 0, stream>>>(parthist, W1, b1, W2, b2, W3, b3, W4, b4, wout);

    const long long n4 = (long long)N_IMG * HW_ELEMS / 4;
    scale_kernel<<<8192, 256, 0, stream>>>(x, wout, (float*)d_out, n4);
}